// Round 13
// baseline (452.008 us; speedup 1.0000x reference)
//
#include <hip/hip_runtime.h>
#include <hip/hip_bf16.h>

#define DEV __device__ __forceinline__

typedef unsigned short u16;
typedef unsigned int u32;

typedef __attribute__((ext_vector_type(8))) short bf16x8;   // 8 bf16 (4 VGPRs)
typedef __attribute__((ext_vector_type(4))) float f32x4;

constexpr float INV_C  = 0.17677669529663687f;   // 1/sqrt(32)
constexpr float INV_S3 = 0.5773502691896258f;    // 1/sqrt(3)

DEV float bf2f(u32 h) { return __uint_as_float(h << 16); }
DEV u32 f2bf_bits(float f) {
  u32 u = __float_as_uint(f);
  u += 0x7fffu + ((u >> 16) & 1u);
  return u >> 16;
}

DEV void st32f(float* __restrict__ p, const float o[32]) {
#pragma unroll
  for (int i = 0; i < 8; ++i) {
    float4 q; q.x=o[4*i+0]; q.y=o[4*i+1]; q.z=o[4*i+2]; q.w=o[4*i+3];
    reinterpret_cast<float4*>(p)[i] = q;
  }
}
DEV void ld32h(const u16* __restrict__ p, float o[32]) {
#pragma unroll
  for (int i = 0; i < 4; ++i) {
    uint4 q = reinterpret_cast<const uint4*>(p)[i];
    u32 w0=q.x, w1=q.y, w2=q.z, w3=q.w;
    o[8*i+0]=bf2f(w0 & 0xffffu); o[8*i+1]=bf2f(w0 >> 16);
    o[8*i+2]=bf2f(w1 & 0xffffu); o[8*i+3]=bf2f(w1 >> 16);
    o[8*i+4]=bf2f(w2 & 0xffffu); o[8*i+5]=bf2f(w2 >> 16);
    o[8*i+6]=bf2f(w3 & 0xffffu); o[8*i+7]=bf2f(w3 >> 16);
  }
}
DEV void st32h(u16* __restrict__ p, const float o[32]) {
#pragma unroll
  for (int i = 0; i < 16; ++i) {
    reinterpret_cast<u32*>(p)[i] = f2bf_bits(o[2*i]) | (f2bf_bits(o[2*i+1]) << 16);
  }
}
// unpack 8 bf16 from a raw uint4
DEV void cv8(uint4 q, float o[8]) {
  o[0]=bf2f(q.x & 0xffffu); o[1]=bf2f(q.x >> 16);
  o[2]=bf2f(q.y & 0xffffu); o[3]=bf2f(q.y >> 16);
  o[4]=bf2f(q.z & 0xffffu); o[5]=bf2f(q.z >> 16);
  o[6]=bf2f(q.w & 0xffffu); o[7]=bf2f(q.w >> 16);
}
// 8-element bf16 slice (16 B, aligned)
DEV void ld8h(const u16* __restrict__ p, float o[8]) {
  cv8(*reinterpret_cast<const uint4*>(p), o);
}
DEV bf16x8 cvt8(const float t[8]) {
  bf16x8 r;
#pragma unroll
  for (int j = 0; j < 8; ++j) r[j] = (short)f2bf_bits(t[j]);
  return r;
}

DEV f32x4 mfma16(bf16x8 a, bf16x8 b, f32x4 c) {
  return __builtin_amdgcn_mfma_f32_16x16x32_bf16(a, b, c, 0, 0, 0);
}

// B-fragment, linT orientation, PRE-SCALED by INV_C: B[k=c][n=d] = W[c*32+d]*INV_C
DEV bf16x8 ldBfrag(const float* __restrict__ W, int kg, int colbase) {
  bf16x8 r;
#pragma unroll
  for (int j = 0; j < 8; ++j)
    r[j] = (short)f2bf_bits(W[(kg*8 + j)*32 + colbase] * INV_C);
  return r;
}
// B-fragment, linN orientation, PRE-SCALED: B[k=v][n=u] = W[u*32+v]*INV_C
DEV bf16x8 ldBfragT(const float* __restrict__ W, int kg, int colbase) {
  bf16x8 r;
  const float* p = W + colbase*32 + kg*8;
#pragma unroll
  for (int j = 0; j < 8; ++j) r[j] = (short)f2bf_bits(p[j] * INV_C);
  return r;
}

DEV float sigmoidf(float x) { return 1.f / (1.f + __expf(-x)); }

// ---- MFMA resblock (wave-private, weights pre-scaled by INV_C at frag load).
// tA: A-frags rows (s,vx,vy,vz)x16; co out = skip + lin2 C-frags.
DEV void mfma_resblock(const float* __restrict__ W7, const bf16x8 tA[4],
                       int col, int kg, float* wbuf, f32x4 co[8]) {
  const f32x4 zero4 = {0.f,0.f,0.f,0.f};
  bf16x8 B1s[2], B1v[2], Bg[2], B2s[2], B2v[2], Bks[2], Bkv[2];
#pragma unroll
  for (int ct = 0; ct < 2; ++ct) {
    int cb = ct*16 + col;
    B1s[ct] = ldBfrag(W7 + 0*1024, kg, cb);
    B1v[ct] = ldBfrag(W7 + 1*1024, kg, cb);
    Bg[ct]  = ldBfrag(W7 + 2*1024, kg, cb);
    B2s[ct] = ldBfrag(W7 + 3*1024, kg, cb);
    B2v[ct] = ldBfrag(W7 + 4*1024, kg, cb);
    Bks[ct] = ldBfrag(W7 + 5*1024, kg, cb);
    Bkv[ct] = ldBfrag(W7 + 6*1024, kg, cb);
  }
  f32x4 c1[8];
#pragma unroll
  for (int i = 0; i < 8; ++i) { c1[i] = zero4; co[i] = zero4; }
#pragma unroll
  for (int rt = 0; rt < 4; ++rt)
#pragma unroll
    for (int ct = 0; ct < 2; ++ct) {
      c1[rt*2+ct] = mfma16(tA[rt], rt==0 ? B1s[ct] : B1v[ct], c1[rt*2+ct]);
      co[rt*2+ct] = mfma16(tA[rt], rt==0 ? Bks[ct] : Bkv[ct], co[rt*2+ct]);
    }
  // c1 is t1 (scale folded into B)

  // gate: transpose t1 s-rows (C->A), MFMA, sigmoid
#pragma unroll
  for (int ct = 0; ct < 2; ++ct)
#pragma unroll
    for (int i = 0; i < 4; ++i)
      wbuf[(kg*4 + i)*36 + ct*16 + col] = c1[ct][i];
  float ag[8];
  *reinterpret_cast<float4*>(&ag[0]) = *reinterpret_cast<const float4*>(&wbuf[col*36 + kg*8]);
  *reinterpret_cast<float4*>(&ag[4]) = *reinterpret_cast<const float4*>(&wbuf[col*36 + kg*8 + 4]);
  bf16x8 Ag = cvt8(ag);
  f32x4 cg0 = mfma16(Ag, Bg[0], zero4);
  f32x4 cg1 = mfma16(Ag, Bg[1], zero4);
  float g0[4], g1[4];
#pragma unroll
  for (int i = 0; i < 4; ++i) {
    g0[i] = sigmoidf(cg0[i]);
    g1[i] = sigmoidf(cg1[i]);
  }

  // t2: silu on s-frags; gate-mult on v-frags (C layouts aligned)
#pragma unroll
  for (int ct = 0; ct < 2; ++ct)
#pragma unroll
    for (int i = 0; i < 4; ++i) {
      float v = c1[ct][i];
      c1[ct][i] = v * sigmoidf(v);
    }
#pragma unroll
  for (int rt = 1; rt < 4; ++rt)
#pragma unroll
    for (int ct = 0; ct < 2; ++ct)
#pragma unroll
      for (int i = 0; i < 4; ++i)
        c1[rt*2+ct][i] *= (ct == 0 ? g0[i] : g1[i]);

  // transpose t2 (C->A)
#pragma unroll
  for (int rt = 0; rt < 4; ++rt)
#pragma unroll
    for (int ct = 0; ct < 2; ++ct)
#pragma unroll
      for (int i = 0; i < 4; ++i)
        wbuf[(rt*16 + kg*4 + i)*36 + ct*16 + col] = c1[rt*2+ct][i];
  bf16x8 t2A[4];
#pragma unroll
  for (int rt = 0; rt < 4; ++rt) {
    float a8[8];
    *reinterpret_cast<float4*>(&a8[0]) = *reinterpret_cast<const float4*>(&wbuf[(rt*16+col)*36 + kg*8]);
    *reinterpret_cast<float4*>(&a8[4]) = *reinterpret_cast<const float4*>(&wbuf[(rt*16+col)*36 + kg*8 + 4]);
    t2A[rt] = cvt8(a8);
  }

  // lin2 accumulate onto skip (scale folded)
#pragma unroll
  for (int rt = 0; rt < 4; ++rt)
#pragma unroll
    for (int ct = 0; ct < 2; ++ct)
      co[rt*2+ct] = mfma16(t2A[rt], rt==0 ? B2s[ct] : B2v[ct], co[rt*2+ct]);
}

// Scratch (bf16), SPLIT:
// wsE per node (512): A_s@0 A_v@32+32x | R_s@128 R_v@160+32x | B0@256 Vr1@288+32x Vr2@384+32x B3@480
// wsD per node (512): DS_s@0 DS_v@32+32x | Q_s@128 Q_v@160+32x | sr0@256 vr1@288+32x vr2@384+32x sr3@480

// ============ nodeA: per-wave task = (job, 16-node tile), zero barriers ============
// jobs: 0 res0->E.A, 1 res2->E.R, 2 res3->D.DS, 3 res5->D.Q, 4 tp1->E.B, 5 tp0->D.T
__global__ __launch_bounds__(256) void nodeA_kernel(
    const float* __restrict__ node_s, const float* __restrict__ node_v,
    const float* __restrict__ tpw, const float* __restrict__ resw,
    u16* __restrict__ wsE, u16* __restrict__ wsD, int N, int ntN)
{
  __shared__ __align__(16) float sbuf[9216];
  const int lane = threadIdx.x & 63;
  const int wave = threadIdx.x >> 6;
  float* wbuf = sbuf + wave*2304;
  const int col = lane & 15;
  const int kg  = lane >> 4;

  const int task = blockIdx.x*4 + wave;
  const int job  = task / ntN;
  const int tile = task - job*ntN;
  if (job >= 6) return;

  const int n0 = tile*16 + col;
  const int nc = (n0 < N) ? n0 : (N-1);
  bf16x8 fA[4];
  {
    float t[8];
    const float* ps = node_s + (size_t)nc*32 + kg*8;
#pragma unroll
    for (int j = 0; j < 8; ++j) t[j] = ps[j];
    fA[0] = cvt8(t);
    const float* pv = node_v + (size_t)nc*96 + kg*24;
#pragma unroll
    for (int x = 0; x < 3; ++x) {
      float tv[8];
#pragma unroll
      for (int j = 0; j < 8; ++j) tv[j] = pv[j*3 + x];
      fA[x+1] = cvt8(tv);
    }
  }

  const int eloc = lane >> 2, comp = lane & 3;
  const int n2 = tile*16 + eloc;

  if (job < 4) {
    const int rbi  = (job==0) ? 0 : (job==1) ? 2 : (job==2) ? 3 : 5;
    u16* bp = (job < 2) ? wsE : wsD;
    const int ooff = ((job & 1) == 0) ? 0 : 128;
    f32x4 co[8];
    mfma_resblock(resw + rbi*7168, fA, col, kg, wbuf, co);
#pragma unroll
    for (int rt = 0; rt < 4; ++rt)
#pragma unroll
      for (int ct = 0; ct < 2; ++ct)
#pragma unroll
        for (int i = 0; i < 4; ++i)
          wbuf[(rt*16 + kg*4 + i)*33 + ct*16 + col] = co[rt*2+ct][i];
    if (n2 < N) {
      float o[32];
      const float* rp = &wbuf[(comp*16 + eloc)*33];
#pragma unroll
      for (int m = 0; m < 32; ++m) o[m] = rp[m];
      st32h(bp + (size_t)n2*512 + ooff + comp*32, o);
    }
  } else {
    const float* Wt = (job==4) ? tpw + 4096 : tpw;
    u16* bp = (job==4) ? wsE : wsD;
    bf16x8 Bw[4][2];
#pragma unroll
    for (int m = 0; m < 4; ++m)
#pragma unroll
      for (int ct = 0; ct < 2; ++ct)
        Bw[m][ct] = ldBfragT(Wt + m*1024, kg, ct*16 + col);
    const f32x4 zero4 = {0.f,0.f,0.f,0.f};
    // pass1: rt0 x W0 (->@256), rt1-3 x W1 (->@288+32x)
    {
      f32x4 c[8];
#pragma unroll
      for (int i = 0; i < 8; ++i) c[i] = zero4;
#pragma unroll
      for (int rt = 0; rt < 4; ++rt)
#pragma unroll
        for (int ct = 0; ct < 2; ++ct)
          c[rt*2+ct] = mfma16(fA[rt], rt==0 ? Bw[0][ct] : Bw[1][ct], c[rt*2+ct]);
#pragma unroll
      for (int rt = 0; rt < 4; ++rt)
#pragma unroll
        for (int ct = 0; ct < 2; ++ct)
#pragma unroll
          for (int i = 0; i < 4; ++i)
            wbuf[(rt*16 + kg*4 + i)*33 + ct*16 + col] = c[rt*2+ct][i];
      if (n2 < N) {
        float o[32];
        const float* rp = &wbuf[(comp*16 + eloc)*33];
#pragma unroll
        for (int m = 0; m < 32; ++m) o[m] = rp[m];
        st32h(bp + (size_t)n2*512 + 256 + comp*32, o);
      }
    }
    // pass2: rt0 x W3 (->@480), rt1-3 x W2 (->@384+32x)
    {
      f32x4 c[8];
#pragma unroll
      for (int i = 0; i < 8; ++i) c[i] = zero4;
#pragma unroll
      for (int rt = 0; rt < 4; ++rt)
#pragma unroll
        for (int ct = 0; ct < 2; ++ct)
          c[rt*2+ct] = mfma16(fA[rt], rt==0 ? Bw[3][ct] : Bw[2][ct], c[rt*2+ct]);
#pragma unroll
      for (int rt = 0; rt < 4; ++rt)
#pragma unroll
        for (int ct = 0; ct < 2; ++ct)
#pragma unroll
          for (int i = 0; i < 4; ++i)
            wbuf[(rt*16 + kg*4 + i)*33 + ct*16 + col] = c[rt*2+ct][i];
      if (n2 < N) {
        float o[32];
        const float* rp = &wbuf[(comp*16 + eloc)*33];
#pragma unroll
        for (int m = 0; m < 32; ++m) o[m] = rp[m];
        const int off = (comp==0) ? 480 : 384 + 32*(comp-1);
        st32h(bp + (size_t)n2*512 + off, o);
      }
    }
  }
}

// ============ merged kernel: edge tiles (blocks < egB) + nodeB tiles ============
// amdgpu_waves_per_eu(4,4): pin the VGPR budget at 128 (4 waves/SIMD) — min=max
// so the backend neither stays at 3 waves (132 regs) nor over-shrinks to 64 (r5 spill).
__global__ __launch_bounds__(256)
__attribute__((amdgpu_waves_per_eu(4, 4)))
void edgeB_kernel(
    const int* __restrict__ ei, const float* __restrict__ resw,
    const u16* __restrict__ wsE, const u16* __restrict__ wsD,
    float* __restrict__ offs, float* __restrict__ offv,
    float* __restrict__ dgs, float* __restrict__ dgv,
    int E, int ntE, int N, int ntN, int egB)
{
  __shared__ __align__(16) float sbuf[9216];
  const int lane = threadIdx.x & 63;
  const int wave = threadIdx.x >> 6;
  float* wbuf = sbuf + wave*2304;
  const int col = lane & 15;
  const int kg  = lane >> 4;
  const f32x4 zero4 = {0.f, 0.f, 0.f, 0.f};

  if ((int)blockIdx.x >= egB) {
    // -------- nodeB path: TP combine + res4 + Q -> dg --------
    const int tile = ((int)blockIdx.x - egB)*4 + wave;
    if (tile >= ntN) return;
    const int n0 = tile*16 + col;
    const int nc = (n0 < N) ? n0 : (N-1);
    const u16* P = wsD + (size_t)nc*512 + kg*8;

    float DSs[8], DSv0[8], DSv1[8], DSv2[8], b[8], acc[8], t[8];
    ld8h(P + 0,  DSs);
    ld8h(P + 32, DSv0);
    ld8h(P + 64, DSv1);
    ld8h(P + 96, DSv2);

    bf16x8 tA[4];
    ld8h(P + 256, b);                               // sr0
#pragma unroll
    for (int j = 0; j < 8; ++j) t[j] = DSs[j]*b[j];
    ld8h(P + 288, b);                               // vr1_x
#pragma unroll
    for (int j = 0; j < 8; ++j) acc[j] = DSv0[j]*b[j];
    ld8h(P + 320, b);
#pragma unroll
    for (int j = 0; j < 8; ++j) acc[j] = __builtin_fmaf(DSv1[j], b[j], acc[j]);
    ld8h(P + 352, b);
#pragma unroll
    for (int j = 0; j < 8; ++j) acc[j] = __builtin_fmaf(DSv2[j], b[j], acc[j]);
#pragma unroll
    for (int j = 0; j < 8; ++j) t[j] = __builtin_fmaf(acc[j], INV_S3, t[j]);
    tA[0] = cvt8(t);

    float sr3[8];
    ld8h(P + 480, sr3);
    ld8h(P + 384, b);
#pragma unroll
    for (int j = 0; j < 8; ++j) t[j] = DSs[j]*b[j] + DSv0[j]*sr3[j];
    tA[1] = cvt8(t);
    ld8h(P + 416, b);
#pragma unroll
    for (int j = 0; j < 8; ++j) t[j] = DSs[j]*b[j] + DSv1[j]*sr3[j];
    tA[2] = cvt8(t);
    ld8h(P + 448, b);
#pragma unroll
    for (int j = 0; j < 8; ++j) t[j] = DSs[j]*b[j] + DSv2[j]*sr3[j];
    tA[3] = cvt8(t);

    f32x4 co[8];
    mfma_resblock(resw + 4*7168, tA, col, kg, wbuf, co);

#pragma unroll
    for (int rt = 0; rt < 4; ++rt)
#pragma unroll
      for (int ct = 0; ct < 2; ++ct)
#pragma unroll
        for (int i = 0; i < 4; ++i)
          wbuf[(rt*16 + kg*4 + i)*33 + ct*16 + col] = co[rt*2+ct][i];

    const int eloc = lane >> 2, comp = lane & 3;
    const int n2 = tile*16 + eloc;
    const int nc2 = (n2 < N) ? n2 : (N-1);
    float o[32];
    {
      const float* rp = &wbuf[(comp*16 + eloc)*33];
#pragma unroll
      for (int m = 0; m < 32; ++m) o[m] = rp[m];
    }
    {
      float q[32];
      ld32h(wsD + (size_t)nc2*512 + 128 + comp*32, q);
#pragma unroll
      for (int c = 0; c < 32; ++c) o[c] += q[c];
    }
    if (comp == 0) {
      if (n2 < N) st32f(dgs + (size_t)n2*32, o);
    } else {
#pragma unroll
      for (int c = 0; c < 32; ++c) wbuf[eloc*97 + 3*c + (comp-1)] = o[c];
    }
    {
      const size_t obase = (size_t)tile * 1536;
#pragma unroll
      for (int i = 0; i < 6; ++i) {
        int s = i*64 + lane;
        int row = s / 24, c4 = s - row*24;
        const float* sp = &wbuf[row*97 + c4*4];
        float4 q; q.x = sp[0]; q.y = sp[1]; q.z = sp[2]; q.w = sp[3];
        if (tile*16 + row < N)
          *reinterpret_cast<float4*>(dgv + obase + (size_t)s*4) = q;
      }
    }
    return;
  }

  // -------- edge path --------
  const float* W = resw + 7168;
  bf16x8 Bs1[2], Bv1[2], Bg[2], Bl2s[2], Bl2v[2], Bsks[2], Bskv[2];
#pragma unroll
  for (int ct = 0; ct < 2; ++ct) {
    int cb = ct*16 + col;
    Bs1[ct]  = ldBfrag(W + 0*1024, kg, cb);
    Bv1[ct]  = ldBfrag(W + 1*1024, kg, cb);
    Bg[ct]   = ldBfrag(W + 2*1024, kg, cb);
    Bl2s[ct] = ldBfrag(W + 3*1024, kg, cb);
    Bl2v[ct] = ldBfrag(W + 4*1024, kg, cb);
    Bsks[ct] = ldBfrag(W + 5*1024, kg, cb);
    Bskv[ct] = ldBfrag(W + 6*1024, kg, cb);
  }

  const int wstride = egB*4;
  int tile = blockIdx.x*4 + wave;
  if (tile >= ntE) return;

  // prefetch first tile: indices + dst A-rows (raw)
  int sn_n, dn_n;
  uint4 dA0, dA1, dA2, dA3;
  {
    int e = tile*16 + col;
    int ec = (e < E) ? e : (E-1);
    sn_n = ei[ec]; dn_n = ei[(size_t)E + ec];
    const u16* Dp = wsE + (size_t)dn_n*512 + kg*8;
    dA0 = *reinterpret_cast<const uint4*>(Dp +  0);
    dA1 = *reinterpret_cast<const uint4*>(Dp + 32);
    dA2 = *reinterpret_cast<const uint4*>(Dp + 64);
    dA3 = *reinterpret_cast<const uint4*>(Dp + 96);
  }

  for (;;) {
    const int ctile = tile;
    const int sn = sn_n;
    uint4 cA0 = dA0, cA1 = dA1, cA2 = dA2, cA3 = dA3;

    tile += wstride;
    if (tile < ntE) {              // issue next-tile prefetch
      int e = tile*16 + col;
      int ec = (e < E) ? e : (E-1);
      sn_n = ei[ec]; dn_n = ei[(size_t)E + ec];
      const u16* Dp = wsE + (size_t)dn_n*512 + kg*8;
      dA0 = *reinterpret_cast<const uint4*>(Dp +  0);
      dA1 = *reinterpret_cast<const uint4*>(Dp + 32);
      dA2 = *reinterpret_cast<const uint4*>(Dp + 64);
      dA3 = *reinterpret_cast<const uint4*>(Dp + 96);
    }

    // ---- TP combine (dst rows from prefetch, src rows loaded now) ----
    float As[8], Av0[8], Av1[8], Av2[8], b[8], acc[8], t[8];
    cv8(cA0, As); cv8(cA1, Av0); cv8(cA2, Av1); cv8(cA3, Av2);

    const u16* S = wsE + (size_t)sn*512 + kg*8;
    bf16x8 tA[4];
    ld8h(S + 256, b);
#pragma unroll
    for (int j = 0; j < 8; ++j) t[j] = As[j]*b[j];
    ld8h(S + 288, b);
#pragma unroll
    for (int j = 0; j < 8; ++j) acc[j] = Av0[j]*b[j];
    ld8h(S + 320, b);
#pragma unroll
    for (int j = 0; j < 8; ++j) acc[j] = __builtin_fmaf(Av1[j], b[j], acc[j]);
    ld8h(S + 352, b);
#pragma unroll
    for (int j = 0; j < 8; ++j) acc[j] = __builtin_fmaf(Av2[j], b[j], acc[j]);
#pragma unroll
    for (int j = 0; j < 8; ++j) t[j] = __builtin_fmaf(acc[j], INV_S3, t[j]);
    tA[0] = cvt8(t);

    ld8h(S + 480, acc);                         // B3
    ld8h(S + 384, b);
#pragma unroll
    for (int j = 0; j < 8; ++j) t[j] = As[j]*b[j] + Av0[j]*acc[j];
    tA[1] = cvt8(t);
    ld8h(S + 416, b);
#pragma unroll
    for (int j = 0; j < 8; ++j) t[j] = As[j]*b[j] + Av1[j]*acc[j];
    tA[2] = cvt8(t);
    ld8h(S + 448, b);
#pragma unroll
    for (int j = 0; j < 8; ++j) t[j] = As[j]*b[j] + Av2[j]*acc[j];
    tA[3] = cvt8(t);

    // ---- resblock res_w[1] (inline; weights pre-scaled) ----
    f32x4 c1[8], co[8];
#pragma unroll
    for (int i = 0; i < 8; ++i) { c1[i] = zero4; co[i] = zero4; }
#pragma unroll
    for (int rt = 0; rt < 4; ++rt) {
#pragma unroll
      for (int ct = 0; ct < 2; ++ct) {
        c1[rt*2+ct] = mfma16(tA[rt], rt==0 ? Bs1[ct] : Bv1[ct], c1[rt*2+ct]);
        co[rt*2+ct] = mfma16(tA[rt], rt==0 ? Bsks[ct] : Bskv[ct], co[rt*2+ct]);
      }
    }

#pragma unroll
    for (int ct = 0; ct < 2; ++ct)
#pragma unroll
      for (int i = 0; i < 4; ++i)
        wbuf[(kg*4 + i)*36 + ct*16 + col] = c1[ct][i];
    float ag[8];
    *reinterpret_cast<float4*>(&ag[0]) = *reinterpret_cast<const float4*>(&wbuf[col*36 + kg*8]);
    *reinterpret_cast<float4*>(&ag[4]) = *reinterpret_cast<const float4*>(&wbuf[col*36 + kg*8 + 4]);
    bf16x8 Ag = cvt8(ag);
    f32x4 cg0 = mfma16(Ag, Bg[0], zero4);
    f32x4 cg1 = mfma16(Ag, Bg[1], zero4);
    float g0[4], g1[4];
#pragma unroll
    for (int i = 0; i < 4; ++i) {
      g0[i] = sigmoidf(cg0[i]);
      g1[i] = sigmoidf(cg1[i]);
    }

#pragma unroll
    for (int ct = 0; ct < 2; ++ct)
#pragma unroll
      for (int i = 0; i < 4; ++i) {
        float v = c1[ct][i];
        c1[ct][i] = v * sigmoidf(v);
      }
#pragma unroll
    for (int rt = 1; rt < 4; ++rt)
#pragma unroll
      for (int ct = 0; ct < 2; ++ct)
#pragma unroll
        for (int i = 0; i < 4; ++i)
          c1[rt*2+ct][i] *= (ct == 0 ? g0[i] : g1[i]);

#pragma unroll
    for (int rt = 0; rt < 4; ++rt)
#pragma unroll
      for (int ct = 0; ct < 2; ++ct)
#pragma unroll
        for (int i = 0; i < 4; ++i)
          wbuf[(rt*16 + kg*4 + i)*36 + ct*16 + col] = c1[rt*2+ct][i];
    bf16x8 t2A[4];
#pragma unroll
    for (int rt = 0; rt < 4; ++rt) {
      float a8[8];
      *reinterpret_cast<float4*>(&a8[0]) = *reinterpret_cast<const float4*>(&wbuf[(rt*16+col)*36 + kg*8]);
      *reinterpret_cast<float4*>(&a8[4]) = *reinterpret_cast<const float4*>(&wbuf[(rt*16+col)*36 + kg*8 + 4]);
      t2A[rt] = cvt8(a8);
    }

#pragma unroll
    for (int rt = 0; rt < 4; ++rt)
#pragma unroll
      for (int ct = 0; ct < 2; ++ct)
        co[rt*2+ct] = mfma16(t2A[rt], rt==0 ? Bl2s[ct] : Bl2v[ct], co[rt*2+ct]);

    // ---- epilogue: C -> rows, +R, store ----
#pragma unroll
    for (int rt = 0; rt < 4; ++rt)
#pragma unroll
      for (int ct = 0; ct < 2; ++ct)
#pragma unroll
        for (int i = 0; i < 4; ++i)
          wbuf[(rt*16 + kg*4 + i)*33 + ct*16 + col] = co[rt*2+ct][i];

    const int eloc = lane >> 2, comp = lane & 3;
    float o[32];
    {
      const float* rp = &wbuf[(comp*16 + eloc)*33];
#pragma unroll
      for (int m = 0; m < 32; ++m) o[m] = rp[m];
    }
    int e2 = ctile*16 + eloc;
    int ec2 = (e2 < E) ? e2 : (E - 1);
    int dn2 = ei[(size_t)E + ec2];
    {
      float r[32];
      ld32h(wsE + (size_t)dn2*512 + 128 + comp*32, r);
#pragma unroll
      for (int c = 0; c < 32; ++c) o[c] += r[c];
    }
    if (comp == 0) {
      if (e2 < E) st32f(offs + (size_t)e2*32, o);
    } else {
#pragma unroll
      for (int c = 0; c < 32; ++c) wbuf[eloc*97 + 3*c + (comp-1)] = o[c];
    }
    {
      const size_t obase = (size_t)ctile * 1536;
#pragma unroll
      for (int i = 0; i < 6; ++i) {
        int s = i*64 + lane;
        int row = s / 24, c4 = s - row*24;
        const float* sp = &wbuf[row*97 + c4*4];
        float4 q; q.x = sp[0]; q.y = sp[1]; q.z = sp[2]; q.w = sp[3];
        if (ctile*16 + row < E)
          *reinterpret_cast<float4*>(offv + obase + (size_t)s*4) = q;
      }
    }

    if (tile >= ntE) break;
  }
}

extern "C" void kernel_launch(void* const* d_in, const int* in_sizes, int n_in,
                              void* d_out, int out_size, void* d_ws, size_t ws_size,
                              hipStream_t stream) {
  const float* node_s = (const float*)d_in[0];
  const float* node_v = (const float*)d_in[1];
  const float* tpw    = (const float*)d_in[2];
  const float* resw   = (const float*)d_in[3];
  const int*   ei     = (const int*)d_in[4];
  const int N = in_sizes[0] / 32;
  const int E = in_sizes[4] / 2;

  float* out  = (float*)d_out;
  float* dgs  = out;
  float* dgv  = out + (size_t)N*32;
  float* offs = out + (size_t)N*128;
  float* offv = offs + (size_t)E*32;

  u16* wsE = (u16*)d_ws;               // N*512 bf16 (edge-read data)
  u16* wsD = wsE + (size_t)N*512;      // N*512 bf16 (diag data)

  const int ntN = (N + 15) / 16;
  const int ntE = (E + 15) / 16;

  const int aBlocks = (6*ntN + 3) / 4;
  const int bBlocks = (ntN + 3) / 4;
  int egB = (ntE + 3) / 4; if (egB > 4096) egB = 4096;

  nodeA_kernel<<<aBlocks, 256, 0, stream>>>(node_s, node_v, tpw, resw,
                                            wsE, wsD, N, ntN);
  edgeB_kernel<<<egB + bBlocks, 256, 0, stream>>>(ei, resw, wsE, wsD,
                                                  offs, offv, dgs, dgv,
                                                  E, ntE, N, ntN, egB);
}

// Round 14
// 300.146 us; speedup vs baseline: 1.5060x; 1.5060x over previous
//
#include <hip/hip_runtime.h>
#include <hip/hip_bf16.h>

#define DEV __device__ __forceinline__

typedef unsigned short u16;
typedef unsigned int u32;

typedef __attribute__((ext_vector_type(8))) short bf16x8;   // 8 bf16 (4 VGPRs)
typedef __attribute__((ext_vector_type(4))) float f32x4;

constexpr float INV_C  = 0.17677669529663687f;   // 1/sqrt(32)
constexpr float INV_S3 = 0.5773502691896258f;    // 1/sqrt(3)

DEV float bf2f(u32 h) { return __uint_as_float(h << 16); }
DEV u32 f2bf_bits(float f) {
  u32 u = __float_as_uint(f);
  u += 0x7fffu + ((u >> 16) & 1u);
  return u >> 16;
}

DEV void st32f(float* __restrict__ p, const float o[32]) {
#pragma unroll
  for (int i = 0; i < 8; ++i) {
    float4 q; q.x=o[4*i+0]; q.y=o[4*i+1]; q.z=o[4*i+2]; q.w=o[4*i+3];
    reinterpret_cast<float4*>(p)[i] = q;
  }
}
DEV void ld32h(const u16* __restrict__ p, float o[32]) {
#pragma unroll
  for (int i = 0; i < 4; ++i) {
    uint4 q = reinterpret_cast<const uint4*>(p)[i];
    u32 w0=q.x, w1=q.y, w2=q.z, w3=q.w;
    o[8*i+0]=bf2f(w0 & 0xffffu); o[8*i+1]=bf2f(w0 >> 16);
    o[8*i+2]=bf2f(w1 & 0xffffu); o[8*i+3]=bf2f(w1 >> 16);
    o[8*i+4]=bf2f(w2 & 0xffffu); o[8*i+5]=bf2f(w2 >> 16);
    o[8*i+6]=bf2f(w3 & 0xffffu); o[8*i+7]=bf2f(w3 >> 16);
  }
}
DEV void st32h(u16* __restrict__ p, const float o[32]) {
#pragma unroll
  for (int i = 0; i < 16; ++i) {
    reinterpret_cast<u32*>(p)[i] = f2bf_bits(o[2*i]) | (f2bf_bits(o[2*i+1]) << 16);
  }
}
// unpack 8 bf16 from a raw uint4
DEV void cv8(uint4 q, float o[8]) {
  o[0]=bf2f(q.x & 0xffffu); o[1]=bf2f(q.x >> 16);
  o[2]=bf2f(q.y & 0xffffu); o[3]=bf2f(q.y >> 16);
  o[4]=bf2f(q.z & 0xffffu); o[5]=bf2f(q.z >> 16);
  o[6]=bf2f(q.w & 0xffffu); o[7]=bf2f(q.w >> 16);
}
// 8-element bf16 slice (16 B, aligned)
DEV void ld8h(const u16* __restrict__ p, float o[8]) {
  cv8(*reinterpret_cast<const uint4*>(p), o);
}
DEV bf16x8 cvt8(const float t[8]) {
  bf16x8 r;
#pragma unroll
  for (int j = 0; j < 8; ++j) r[j] = (short)f2bf_bits(t[j]);
  return r;
}

DEV f32x4 mfma16(bf16x8 a, bf16x8 b, f32x4 c) {
  return __builtin_amdgcn_mfma_f32_16x16x32_bf16(a, b, c, 0, 0, 0);
}

// B-fragment, linT orientation, PRE-SCALED by INV_C: B[k=c][n=d] = W[c*32+d]*INV_C
DEV bf16x8 ldBfrag(const float* __restrict__ W, int kg, int colbase) {
  bf16x8 r;
#pragma unroll
  for (int j = 0; j < 8; ++j)
    r[j] = (short)f2bf_bits(W[(kg*8 + j)*32 + colbase] * INV_C);
  return r;
}
// B-fragment, linN orientation, PRE-SCALED: B[k=v][n=u] = W[u*32+v]*INV_C
DEV bf16x8 ldBfragT(const float* __restrict__ W, int kg, int colbase) {
  bf16x8 r;
  const float* p = W + colbase*32 + kg*8;
#pragma unroll
  for (int j = 0; j < 8; ++j) r[j] = (short)f2bf_bits(p[j] * INV_C);
  return r;
}

DEV float sigmoidf(float x) { return 1.f / (1.f + __expf(-x)); }

// ---- MFMA resblock (wave-private, weights pre-scaled by INV_C at frag load).
// tA: A-frags rows (s,vx,vy,vz)x16; co out = skip + lin2 C-frags.
DEV void mfma_resblock(const float* __restrict__ W7, const bf16x8 tA[4],
                       int col, int kg, float* wbuf, f32x4 co[8]) {
  const f32x4 zero4 = {0.f,0.f,0.f,0.f};
  bf16x8 B1s[2], B1v[2], Bg[2], B2s[2], B2v[2], Bks[2], Bkv[2];
#pragma unroll
  for (int ct = 0; ct < 2; ++ct) {
    int cb = ct*16 + col;
    B1s[ct] = ldBfrag(W7 + 0*1024, kg, cb);
    B1v[ct] = ldBfrag(W7 + 1*1024, kg, cb);
    Bg[ct]  = ldBfrag(W7 + 2*1024, kg, cb);
    B2s[ct] = ldBfrag(W7 + 3*1024, kg, cb);
    B2v[ct] = ldBfrag(W7 + 4*1024, kg, cb);
    Bks[ct] = ldBfrag(W7 + 5*1024, kg, cb);
    Bkv[ct] = ldBfrag(W7 + 6*1024, kg, cb);
  }
  f32x4 c1[8];
#pragma unroll
  for (int i = 0; i < 8; ++i) { c1[i] = zero4; co[i] = zero4; }
#pragma unroll
  for (int rt = 0; rt < 4; ++rt)
#pragma unroll
    for (int ct = 0; ct < 2; ++ct) {
      c1[rt*2+ct] = mfma16(tA[rt], rt==0 ? B1s[ct] : B1v[ct], c1[rt*2+ct]);
      co[rt*2+ct] = mfma16(tA[rt], rt==0 ? Bks[ct] : Bkv[ct], co[rt*2+ct]);
    }
  // c1 is t1 (scale folded into B)

  // gate: transpose t1 s-rows (C->A), MFMA, sigmoid
#pragma unroll
  for (int ct = 0; ct < 2; ++ct)
#pragma unroll
    for (int i = 0; i < 4; ++i)
      wbuf[(kg*4 + i)*36 + ct*16 + col] = c1[ct][i];
  float ag[8];
  *reinterpret_cast<float4*>(&ag[0]) = *reinterpret_cast<const float4*>(&wbuf[col*36 + kg*8]);
  *reinterpret_cast<float4*>(&ag[4]) = *reinterpret_cast<const float4*>(&wbuf[col*36 + kg*8 + 4]);
  bf16x8 Ag = cvt8(ag);
  f32x4 cg0 = mfma16(Ag, Bg[0], zero4);
  f32x4 cg1 = mfma16(Ag, Bg[1], zero4);
  float g0[4], g1[4];
#pragma unroll
  for (int i = 0; i < 4; ++i) {
    g0[i] = sigmoidf(cg0[i]);
    g1[i] = sigmoidf(cg1[i]);
  }

  // t2: silu on s-frags; gate-mult on v-frags (C layouts aligned)
#pragma unroll
  for (int ct = 0; ct < 2; ++ct)
#pragma unroll
    for (int i = 0; i < 4; ++i) {
      float v = c1[ct][i];
      c1[ct][i] = v * sigmoidf(v);
    }
#pragma unroll
  for (int rt = 1; rt < 4; ++rt)
#pragma unroll
    for (int ct = 0; ct < 2; ++ct)
#pragma unroll
      for (int i = 0; i < 4; ++i)
        c1[rt*2+ct][i] *= (ct == 0 ? g0[i] : g1[i]);

  // transpose t2 (C->A)
#pragma unroll
  for (int rt = 0; rt < 4; ++rt)
#pragma unroll
    for (int ct = 0; ct < 2; ++ct)
#pragma unroll
      for (int i = 0; i < 4; ++i)
        wbuf[(rt*16 + kg*4 + i)*36 + ct*16 + col] = c1[rt*2+ct][i];
  bf16x8 t2A[4];
#pragma unroll
  for (int rt = 0; rt < 4; ++rt) {
    float a8[8];
    *reinterpret_cast<float4*>(&a8[0]) = *reinterpret_cast<const float4*>(&wbuf[(rt*16+col)*36 + kg*8]);
    *reinterpret_cast<float4*>(&a8[4]) = *reinterpret_cast<const float4*>(&wbuf[(rt*16+col)*36 + kg*8 + 4]);
    t2A[rt] = cvt8(a8);
  }

  // lin2 accumulate onto skip (scale folded)
#pragma unroll
  for (int rt = 0; rt < 4; ++rt)
#pragma unroll
    for (int ct = 0; ct < 2; ++ct)
      co[rt*2+ct] = mfma16(t2A[rt], rt==0 ? B2s[ct] : B2v[ct], co[rt*2+ct]);
}

// Scratch (bf16), SPLIT:
// wsE per node (512): A_s@0 A_v@32+32x | R_s@128 R_v@160+32x | B0@256 Vr1@288+32x Vr2@384+32x B3@480
// wsD per node (512): DS_s@0 DS_v@32+32x | Q_s@128 Q_v@160+32x | sr0@256 vr1@288+32x vr2@384+32x sr3@480

// ============ nodeA: per-wave task = (job, 16-node tile), zero barriers ============
// jobs: 0 res0->E.A, 1 res2->E.R, 2 res3->D.DS, 3 res5->D.Q, 4 tp1->E.B, 5 tp0->D.T
__global__ __launch_bounds__(256) void nodeA_kernel(
    const float* __restrict__ node_s, const float* __restrict__ node_v,
    const float* __restrict__ tpw, const float* __restrict__ resw,
    u16* __restrict__ wsE, u16* __restrict__ wsD, int N, int ntN)
{
  __shared__ __align__(16) float sbuf[9216];
  const int lane = threadIdx.x & 63;
  const int wave = threadIdx.x >> 6;
  float* wbuf = sbuf + wave*2304;
  const int col = lane & 15;
  const int kg  = lane >> 4;

  const int task = blockIdx.x*4 + wave;
  const int job  = task / ntN;
  const int tile = task - job*ntN;
  if (job >= 6) return;

  const int n0 = tile*16 + col;
  const int nc = (n0 < N) ? n0 : (N-1);
  bf16x8 fA[4];
  {
    float t[8];
    const float* ps = node_s + (size_t)nc*32 + kg*8;
#pragma unroll
    for (int j = 0; j < 8; ++j) t[j] = ps[j];
    fA[0] = cvt8(t);
    const float* pv = node_v + (size_t)nc*96 + kg*24;
#pragma unroll
    for (int x = 0; x < 3; ++x) {
      float tv[8];
#pragma unroll
      for (int j = 0; j < 8; ++j) tv[j] = pv[j*3 + x];
      fA[x+1] = cvt8(tv);
    }
  }

  const int eloc = lane >> 2, comp = lane & 3;
  const int n2 = tile*16 + eloc;

  if (job < 4) {
    const int rbi  = (job==0) ? 0 : (job==1) ? 2 : (job==2) ? 3 : 5;
    u16* bp = (job < 2) ? wsE : wsD;
    const int ooff = ((job & 1) == 0) ? 0 : 128;
    f32x4 co[8];
    mfma_resblock(resw + rbi*7168, fA, col, kg, wbuf, co);
#pragma unroll
    for (int rt = 0; rt < 4; ++rt)
#pragma unroll
      for (int ct = 0; ct < 2; ++ct)
#pragma unroll
        for (int i = 0; i < 4; ++i)
          wbuf[(rt*16 + kg*4 + i)*33 + ct*16 + col] = co[rt*2+ct][i];
    if (n2 < N) {
      float o[32];
      const float* rp = &wbuf[(comp*16 + eloc)*33];
#pragma unroll
      for (int m = 0; m < 32; ++m) o[m] = rp[m];
      st32h(bp + (size_t)n2*512 + ooff + comp*32, o);
    }
  } else {
    const float* Wt = (job==4) ? tpw + 4096 : tpw;
    u16* bp = (job==4) ? wsE : wsD;
    bf16x8 Bw[4][2];
#pragma unroll
    for (int m = 0; m < 4; ++m)
#pragma unroll
      for (int ct = 0; ct < 2; ++ct)
        Bw[m][ct] = ldBfragT(Wt + m*1024, kg, ct*16 + col);
    const f32x4 zero4 = {0.f,0.f,0.f,0.f};
    // pass1: rt0 x W0 (->@256), rt1-3 x W1 (->@288+32x)
    {
      f32x4 c[8];
#pragma unroll
      for (int i = 0; i < 8; ++i) c[i] = zero4;
#pragma unroll
      for (int rt = 0; rt < 4; ++rt)
#pragma unroll
        for (int ct = 0; ct < 2; ++ct)
          c[rt*2+ct] = mfma16(fA[rt], rt==0 ? Bw[0][ct] : Bw[1][ct], c[rt*2+ct]);
#pragma unroll
      for (int rt = 0; rt < 4; ++rt)
#pragma unroll
        for (int ct = 0; ct < 2; ++ct)
#pragma unroll
          for (int i = 0; i < 4; ++i)
            wbuf[(rt*16 + kg*4 + i)*33 + ct*16 + col] = c[rt*2+ct][i];
      if (n2 < N) {
        float o[32];
        const float* rp = &wbuf[(comp*16 + eloc)*33];
#pragma unroll
        for (int m = 0; m < 32; ++m) o[m] = rp[m];
        st32h(bp + (size_t)n2*512 + 256 + comp*32, o);
      }
    }
    // pass2: rt0 x W3 (->@480), rt1-3 x W2 (->@384+32x)
    {
      f32x4 c[8];
#pragma unroll
      for (int i = 0; i < 8; ++i) c[i] = zero4;
#pragma unroll
      for (int rt = 0; rt < 4; ++rt)
#pragma unroll
        for (int ct = 0; ct < 2; ++ct)
          c[rt*2+ct] = mfma16(fA[rt], rt==0 ? Bw[3][ct] : Bw[2][ct], c[rt*2+ct]);
#pragma unroll
      for (int rt = 0; rt < 4; ++rt)
#pragma unroll
        for (int ct = 0; ct < 2; ++ct)
#pragma unroll
          for (int i = 0; i < 4; ++i)
            wbuf[(rt*16 + kg*4 + i)*33 + ct*16 + col] = c[rt*2+ct][i];
      if (n2 < N) {
        float o[32];
        const float* rp = &wbuf[(comp*16 + eloc)*33];
#pragma unroll
        for (int m = 0; m < 32; ++m) o[m] = rp[m];
        const int off = (comp==0) ? 480 : 384 + 32*(comp-1);
        st32h(bp + (size_t)n2*512 + off, o);
      }
    }
  }
}

// ============ merged kernel: edge tiles (blocks < egB) + nodeB tiles ============
// No occupancy attributes (r5/r13: any hint collapses VGPR target to 64 and
// spills). Register pressure is instead reduced structurally: the cross-tile
// prefetch window holds only 2 dst rows (A_s, A_v0); A_v1/A_v2 load at loop
// head (still ~200 instrs ahead of first use).
__global__ __launch_bounds__(256) void edgeB_kernel(
    const int* __restrict__ ei, const float* __restrict__ resw,
    const u16* __restrict__ wsE, const u16* __restrict__ wsD,
    float* __restrict__ offs, float* __restrict__ offv,
    float* __restrict__ dgs, float* __restrict__ dgv,
    int E, int ntE, int N, int ntN, int egB)
{
  __shared__ __align__(16) float sbuf[9216];
  const int lane = threadIdx.x & 63;
  const int wave = threadIdx.x >> 6;
  float* wbuf = sbuf + wave*2304;
  const int col = lane & 15;
  const int kg  = lane >> 4;
  const f32x4 zero4 = {0.f, 0.f, 0.f, 0.f};

  if ((int)blockIdx.x >= egB) {
    // -------- nodeB path: TP combine + res4 + Q -> dg --------
    const int tile = ((int)blockIdx.x - egB)*4 + wave;
    if (tile >= ntN) return;
    const int n0 = tile*16 + col;
    const int nc = (n0 < N) ? n0 : (N-1);
    const u16* P = wsD + (size_t)nc*512 + kg*8;

    float DSs[8], DSv0[8], DSv1[8], DSv2[8], b[8], acc[8], t[8];
    ld8h(P + 0,  DSs);
    ld8h(P + 32, DSv0);
    ld8h(P + 64, DSv1);
    ld8h(P + 96, DSv2);

    bf16x8 tA[4];
    ld8h(P + 256, b);                               // sr0
#pragma unroll
    for (int j = 0; j < 8; ++j) t[j] = DSs[j]*b[j];
    ld8h(P + 288, b);                               // vr1_x
#pragma unroll
    for (int j = 0; j < 8; ++j) acc[j] = DSv0[j]*b[j];
    ld8h(P + 320, b);
#pragma unroll
    for (int j = 0; j < 8; ++j) acc[j] = __builtin_fmaf(DSv1[j], b[j], acc[j]);
    ld8h(P + 352, b);
#pragma unroll
    for (int j = 0; j < 8; ++j) acc[j] = __builtin_fmaf(DSv2[j], b[j], acc[j]);
#pragma unroll
    for (int j = 0; j < 8; ++j) t[j] = __builtin_fmaf(acc[j], INV_S3, t[j]);
    tA[0] = cvt8(t);

    float sr3[8];
    ld8h(P + 480, sr3);
    ld8h(P + 384, b);
#pragma unroll
    for (int j = 0; j < 8; ++j) t[j] = DSs[j]*b[j] + DSv0[j]*sr3[j];
    tA[1] = cvt8(t);
    ld8h(P + 416, b);
#pragma unroll
    for (int j = 0; j < 8; ++j) t[j] = DSs[j]*b[j] + DSv1[j]*sr3[j];
    tA[2] = cvt8(t);
    ld8h(P + 448, b);
#pragma unroll
    for (int j = 0; j < 8; ++j) t[j] = DSs[j]*b[j] + DSv2[j]*sr3[j];
    tA[3] = cvt8(t);

    f32x4 co[8];
    mfma_resblock(resw + 4*7168, tA, col, kg, wbuf, co);

#pragma unroll
    for (int rt = 0; rt < 4; ++rt)
#pragma unroll
      for (int ct = 0; ct < 2; ++ct)
#pragma unroll
        for (int i = 0; i < 4; ++i)
          wbuf[(rt*16 + kg*4 + i)*33 + ct*16 + col] = co[rt*2+ct][i];

    const int eloc = lane >> 2, comp = lane & 3;
    const int n2 = tile*16 + eloc;
    const int nc2 = (n2 < N) ? n2 : (N-1);
    float o[32];
    {
      const float* rp = &wbuf[(comp*16 + eloc)*33];
#pragma unroll
      for (int m = 0; m < 32; ++m) o[m] = rp[m];
    }
    {
      float q[32];
      ld32h(wsD + (size_t)nc2*512 + 128 + comp*32, q);
#pragma unroll
      for (int c = 0; c < 32; ++c) o[c] += q[c];
    }
    if (comp == 0) {
      if (n2 < N) st32f(dgs + (size_t)n2*32, o);
    } else {
#pragma unroll
      for (int c = 0; c < 32; ++c) wbuf[eloc*97 + 3*c + (comp-1)] = o[c];
    }
    {
      const size_t obase = (size_t)tile * 1536;
#pragma unroll
      for (int i = 0; i < 6; ++i) {
        int s = i*64 + lane;
        int row = s / 24, c4 = s - row*24;
        const float* sp = &wbuf[row*97 + c4*4];
        float4 q; q.x = sp[0]; q.y = sp[1]; q.z = sp[2]; q.w = sp[3];
        if (tile*16 + row < N)
          *reinterpret_cast<float4*>(dgv + obase + (size_t)s*4) = q;
      }
    }
    return;
  }

  // -------- edge path --------
  const float* W = resw + 7168;
  bf16x8 Bs1[2], Bv1[2], Bg[2], Bl2s[2], Bl2v[2], Bsks[2], Bskv[2];
#pragma unroll
  for (int ct = 0; ct < 2; ++ct) {
    int cb = ct*16 + col;
    Bs1[ct]  = ldBfrag(W + 0*1024, kg, cb);
    Bv1[ct]  = ldBfrag(W + 1*1024, kg, cb);
    Bg[ct]   = ldBfrag(W + 2*1024, kg, cb);
    Bl2s[ct] = ldBfrag(W + 3*1024, kg, cb);
    Bl2v[ct] = ldBfrag(W + 4*1024, kg, cb);
    Bsks[ct] = ldBfrag(W + 5*1024, kg, cb);
    Bskv[ct] = ldBfrag(W + 6*1024, kg, cb);
  }

  const int wstride = egB*4;
  int tile = blockIdx.x*4 + wave;
  if (tile >= ntE) return;

  // prefetch first tile: indices + 2 dst A-rows (raw)
  int sn_n, dn_n;
  uint4 dA0, dA1;
  {
    int e = tile*16 + col;
    int ec = (e < E) ? e : (E-1);
    sn_n = ei[ec]; dn_n = ei[(size_t)E + ec];
    const u16* Dp = wsE + (size_t)dn_n*512 + kg*8;
    dA0 = *reinterpret_cast<const uint4*>(Dp +  0);
    dA1 = *reinterpret_cast<const uint4*>(Dp + 32);
  }

  for (;;) {
    const int ctile = tile;
    const int sn = sn_n;
    const int dn = dn_n;
    uint4 cA0 = dA0, cA1 = dA1;
    // remaining dst rows now (issued ~200 instrs before their use in the TP)
    uint4 cA2, cA3;
    {
      const u16* Dc = wsE + (size_t)dn*512 + kg*8;
      cA2 = *reinterpret_cast<const uint4*>(Dc + 64);
      cA3 = *reinterpret_cast<const uint4*>(Dc + 96);
    }

    tile += wstride;
    if (tile < ntE) {              // issue next-tile prefetch
      int e = tile*16 + col;
      int ec = (e < E) ? e : (E-1);
      sn_n = ei[ec]; dn_n = ei[(size_t)E + ec];
      const u16* Dp = wsE + (size_t)dn_n*512 + kg*8;
      dA0 = *reinterpret_cast<const uint4*>(Dp +  0);
      dA1 = *reinterpret_cast<const uint4*>(Dp + 32);
    }

    // ---- TP combine (dst rows from prefetch, src rows loaded now) ----
    float As[8], Av0[8], Av1[8], Av2[8], b[8], acc[8], t[8];
    cv8(cA0, As); cv8(cA1, Av0); cv8(cA2, Av1); cv8(cA3, Av2);

    const u16* S = wsE + (size_t)sn*512 + kg*8;
    bf16x8 tA[4];
    ld8h(S + 256, b);
#pragma unroll
    for (int j = 0; j < 8; ++j) t[j] = As[j]*b[j];
    ld8h(S + 288, b);
#pragma unroll
    for (int j = 0; j < 8; ++j) acc[j] = Av0[j]*b[j];
    ld8h(S + 320, b);
#pragma unroll
    for (int j = 0; j < 8; ++j) acc[j] = __builtin_fmaf(Av1[j], b[j], acc[j]);
    ld8h(S + 352, b);
#pragma unroll
    for (int j = 0; j < 8; ++j) acc[j] = __builtin_fmaf(Av2[j], b[j], acc[j]);
#pragma unroll
    for (int j = 0; j < 8; ++j) t[j] = __builtin_fmaf(acc[j], INV_S3, t[j]);
    tA[0] = cvt8(t);

    ld8h(S + 480, acc);                         // B3
    ld8h(S + 384, b);
#pragma unroll
    for (int j = 0; j < 8; ++j) t[j] = As[j]*b[j] + Av0[j]*acc[j];
    tA[1] = cvt8(t);
    ld8h(S + 416, b);
#pragma unroll
    for (int j = 0; j < 8; ++j) t[j] = As[j]*b[j] + Av1[j]*acc[j];
    tA[2] = cvt8(t);
    ld8h(S + 448, b);
#pragma unroll
    for (int j = 0; j < 8; ++j) t[j] = As[j]*b[j] + Av2[j]*acc[j];
    tA[3] = cvt8(t);

    // ---- resblock res_w[1] (inline; weights pre-scaled) ----
    f32x4 c1[8], co[8];
#pragma unroll
    for (int i = 0; i < 8; ++i) { c1[i] = zero4; co[i] = zero4; }
#pragma unroll
    for (int rt = 0; rt < 4; ++rt) {
#pragma unroll
      for (int ct = 0; ct < 2; ++ct) {
        c1[rt*2+ct] = mfma16(tA[rt], rt==0 ? Bs1[ct] : Bv1[ct], c1[rt*2+ct]);
        co[rt*2+ct] = mfma16(tA[rt], rt==0 ? Bsks[ct] : Bskv[ct], co[rt*2+ct]);
      }
    }

#pragma unroll
    for (int ct = 0; ct < 2; ++ct)
#pragma unroll
      for (int i = 0; i < 4; ++i)
        wbuf[(kg*4 + i)*36 + ct*16 + col] = c1[ct][i];
    float ag[8];
    *reinterpret_cast<float4*>(&ag[0]) = *reinterpret_cast<const float4*>(&wbuf[col*36 + kg*8]);
    *reinterpret_cast<float4*>(&ag[4]) = *reinterpret_cast<const float4*>(&wbuf[col*36 + kg*8 + 4]);
    bf16x8 Ag = cvt8(ag);
    f32x4 cg0 = mfma16(Ag, Bg[0], zero4);
    f32x4 cg1 = mfma16(Ag, Bg[1], zero4);
    float g0[4], g1[4];
#pragma unroll
    for (int i = 0; i < 4; ++i) {
      g0[i] = sigmoidf(cg0[i]);
      g1[i] = sigmoidf(cg1[i]);
    }

#pragma unroll
    for (int ct = 0; ct < 2; ++ct)
#pragma unroll
      for (int i = 0; i < 4; ++i) {
        float v = c1[ct][i];
        c1[ct][i] = v * sigmoidf(v);
      }
#pragma unroll
    for (int rt = 1; rt < 4; ++rt)
#pragma unroll
      for (int ct = 0; ct < 2; ++ct)
#pragma unroll
        for (int i = 0; i < 4; ++i)
          c1[rt*2+ct][i] *= (ct == 0 ? g0[i] : g1[i]);

#pragma unroll
    for (int rt = 0; rt < 4; ++rt)
#pragma unroll
      for (int ct = 0; ct < 2; ++ct)
#pragma unroll
        for (int i = 0; i < 4; ++i)
          wbuf[(rt*16 + kg*4 + i)*36 + ct*16 + col] = c1[rt*2+ct][i];
    bf16x8 t2A[4];
#pragma unroll
    for (int rt = 0; rt < 4; ++rt) {
      float a8[8];
      *reinterpret_cast<float4*>(&a8[0]) = *reinterpret_cast<const float4*>(&wbuf[(rt*16+col)*36 + kg*8]);
      *reinterpret_cast<float4*>(&a8[4]) = *reinterpret_cast<const float4*>(&wbuf[(rt*16+col)*36 + kg*8 + 4]);
      t2A[rt] = cvt8(a8);
    }

#pragma unroll
    for (int rt = 0; rt < 4; ++rt)
#pragma unroll
      for (int ct = 0; ct < 2; ++ct)
        co[rt*2+ct] = mfma16(t2A[rt], rt==0 ? Bl2s[ct] : Bl2v[ct], co[rt*2+ct]);

    // ---- epilogue: C -> rows, +R, store ----
#pragma unroll
    for (int rt = 0; rt < 4; ++rt)
#pragma unroll
      for (int ct = 0; ct < 2; ++ct)
#pragma unroll
        for (int i = 0; i < 4; ++i)
          wbuf[(rt*16 + kg*4 + i)*33 + ct*16 + col] = co[rt*2+ct][i];

    const int eloc = lane >> 2, comp = lane & 3;
    float o[32];
    {
      const float* rp = &wbuf[(comp*16 + eloc)*33];
#pragma unroll
      for (int m = 0; m < 32; ++m) o[m] = rp[m];
    }
    int e2 = ctile*16 + eloc;
    int ec2 = (e2 < E) ? e2 : (E - 1);
    int dn2 = ei[(size_t)E + ec2];
    {
      float r[32];
      ld32h(wsE + (size_t)dn2*512 + 128 + comp*32, r);
#pragma unroll
      for (int c = 0; c < 32; ++c) o[c] += r[c];
    }
    if (comp == 0) {
      if (e2 < E) st32f(offs + (size_t)e2*32, o);
    } else {
#pragma unroll
      for (int c = 0; c < 32; ++c) wbuf[eloc*97 + 3*c + (comp-1)] = o[c];
    }
    {
      const size_t obase = (size_t)ctile * 1536;
#pragma unroll
      for (int i = 0; i < 6; ++i) {
        int s = i*64 + lane;
        int row = s / 24, c4 = s - row*24;
        const float* sp = &wbuf[row*97 + c4*4];
        float4 q; q.x = sp[0]; q.y = sp[1]; q.z = sp[2]; q.w = sp[3];
        if (ctile*16 + row < E)
          *reinterpret_cast<float4*>(offv + obase + (size_t)s*4) = q;
      }
    }

    if (tile >= ntE) break;
  }
}

extern "C" void kernel_launch(void* const* d_in, const int* in_sizes, int n_in,
                              void* d_out, int out_size, void* d_ws, size_t ws_size,
                              hipStream_t stream) {
  const float* node_s = (const float*)d_in[0];
  const float* node_v = (const float*)d_in[1];
  const float* tpw    = (const float*)d_in[2];
  const float* resw   = (const float*)d_in[3];
  const int*   ei     = (const int*)d_in[4];
  const int N = in_sizes[0] / 32;
  const int E = in_sizes[4] / 2;

  float* out  = (float*)d_out;
  float* dgs  = out;
  float* dgv  = out + (size_t)N*32;
  float* offs = out + (size_t)N*128;
  float* offv = offs + (size_t)E*32;

  u16* wsE = (u16*)d_ws;               // N*512 bf16 (edge-read data)
  u16* wsD = wsE + (size_t)N*512;      // N*512 bf16 (diag data)

  const int ntN = (N + 15) / 16;
  const int ntE = (E + 15) / 16;

  const int aBlocks = (6*ntN + 3) / 4;
  const int bBlocks = (ntN + 3) / 4;
  int egB = (ntE + 3) / 4; if (egB > 4096) egB = 4096;

  nodeA_kernel<<<aBlocks, 256, 0, stream>>>(node_s, node_v, tpw, resw,
                                            wsE, wsD, N, ntN);
  edgeB_kernel<<<egB + bBlocks, 256, 0, stream>>>(ei, resw, wsE, wsD,
                                                  offs, offv, dgs, dgv,
                                                  E, ntE, N, ntN, egB);
}